// Round 1
// baseline (625.515 us; speedup 1.0000x reference)
//
#include <hip/hip_runtime.h>

typedef __bf16 bf16x8 __attribute__((ext_vector_type(8)));
typedef float f32x4 __attribute__((ext_vector_type(4)));
typedef unsigned short ushort8 __attribute__((ext_vector_type(8)));

#define LDS_AS(p) ((__attribute__((address_space(3))) void*)(p))
#define GLB_AS(p) ((const __attribute__((address_space(1))) void*)(p))

__device__ __forceinline__ unsigned short f2bf(float f) {
    union { float f; unsigned u; } v; v.f = f;
    unsigned r = v.u + 0x7fffu + ((v.u >> 16) & 1u);
    return (unsigned short)(r >> 16);
}

// ---------------- weight fp32 -> bf16 conversion ----------------
__global__ __launch_bounds__(256) void convw_kernel(
    const float* __restrict__ wi, const float* __restrict__ wo,
    unsigned short* __restrict__ qw, unsigned short* __restrict__ ow)
{
    const int i = blockIdx.x * 256 + threadIdx.x;
    if (i < 1152 * 384) qw[i] = f2bf(wi[i]);
    if (i < 384 * 384)  ow[i] = f2bf(wo[i]);
}

// ---------------- LayerNorm + window partition + bf16 cast ----------------
// one wave per output row (window order), 4 rows per block
__global__ __launch_bounds__(256) void ln_kernel(
    const float* __restrict__ x, const float* __restrict__ gam,
    const float* __restrict__ bet, unsigned short* __restrict__ y)
{
    const int lane = threadIdx.x & 63;
    const int wv   = threadIdx.x >> 6;
    const int m    = blockIdx.x * 4 + wv;
    const int win  = m / 49, l = m - win * 49;
    const int b = win >> 6, wh = (win >> 3) & 7, ww = win & 7;
    const int i = l / 7, j = l - i * 7;
    const float2* xr = (const float2*)(x + ((size_t)b * 3136 + (wh * 7 + i) * 56 + (ww * 7 + j)) * 384);

    float2 v[3];
    float s = 0.f, ss = 0.f;
#pragma unroll
    for (int t = 0; t < 3; ++t) {
        v[t] = xr[t * 64 + lane];
        s  += v[t].x + v[t].y;
        ss += v[t].x * v[t].x + v[t].y * v[t].y;
    }
#pragma unroll
    for (int d = 1; d < 64; d <<= 1) {
        s  += __shfl_xor(s, d, 64);
        ss += __shfl_xor(ss, d, 64);
    }
    const float mu  = s * (1.f / 384.f);
    const float var = ss * (1.f / 384.f) - mu * mu;
    const float rs  = rsqrtf(var + 1e-5f);

    unsigned* yr = (unsigned*)(y + (size_t)m * 384);
#pragma unroll
    for (int t = 0; t < 3; ++t) {
        const int c = (t * 64 + lane) * 2;
        float a0 = (v[t].x - mu) * rs * gam[c]     + bet[c];
        float a1 = (v[t].y - mu) * rs * gam[c + 1] + bet[c + 1];
        yr[t * 64 + lane] = (unsigned)f2bf(a0) | ((unsigned)f2bf(a1) << 16);
    }
}

// ---------------- 128x128 bf16 MFMA GEMM, K=384, BK=32 ----------------
// C[m,n] = sum_k A[m,k]*Bw[n,k] + bias[n]
// EPI=0: store bf16 to obf[M,N_]. EPI=1: window-reverse remap + residual + fp32 store.
template <int N_, int EPI>
__global__ __launch_bounds__(256) void gemm_kernel(
    const unsigned short* __restrict__ A,
    const unsigned short* __restrict__ Bw,
    const float* __restrict__ bias,
    unsigned short* __restrict__ obf,
    const float* __restrict__ xres,
    float* __restrict__ oflt)
{
    __shared__ unsigned short As[128 * 32];
    __shared__ unsigned short Bs[128 * 32];
    const int lane = threadIdx.x & 63;
    const int wv   = threadIdx.x >> 6;
    const int m0 = blockIdx.y * 128;
    const int n0 = blockIdx.x * 128;
    const int wm = (wv & 1) * 64;
    const int wn = (wv >> 1) * 64;
    const int cl = lane & 15;
    const int qd = lane >> 4;
    const int srow = wv * 16 + (lane >> 2);   // + t*64
    const int scol = (lane & 3) * 8;          // bf16 elems

    f32x4 acc[4][4] = {};

    for (int kb = 0; kb < 12; ++kb) {
        const int k0 = kb * 32;
        __syncthreads();
#pragma unroll
        for (int t = 0; t < 2; ++t) {
            const unsigned short* ga = A  + (size_t)(m0 + t * 64 + srow) * 384 + k0 + scol;
            __builtin_amdgcn_global_load_lds(GLB_AS(ga), LDS_AS(As + (t * 64 + wv * 16) * 32), 16, 0, 0);
            const unsigned short* gb = Bw + (size_t)(n0 + t * 64 + srow) * 384 + k0 + scol;
            __builtin_amdgcn_global_load_lds(GLB_AS(gb), LDS_AS(Bs + (t * 64 + wv * 16) * 32), 16, 0, 0);
        }
        __syncthreads();

        bf16x8 af[4], bfr[4];
#pragma unroll
        for (int mt = 0; mt < 4; ++mt)
            af[mt] = *(const bf16x8*)(As + (wm + mt * 16 + cl) * 32 + qd * 8);
#pragma unroll
        for (int nt = 0; nt < 4; ++nt)
            bfr[nt] = *(const bf16x8*)(Bs + (wn + nt * 16 + cl) * 32 + qd * 8);
#pragma unroll
        for (int mt = 0; mt < 4; ++mt)
#pragma unroll
            for (int nt = 0; nt < 4; ++nt)
                acc[mt][nt] = __builtin_amdgcn_mfma_f32_16x16x32_bf16(af[mt], bfr[nt], acc[mt][nt], 0, 0, 0);
    }

#pragma unroll
    for (int mt = 0; mt < 4; ++mt) {
#pragma unroll
        for (int nt = 0; nt < 4; ++nt) {
            const int col = n0 + wn + nt * 16 + cl;
            const float bv = bias[col];
#pragma unroll
            for (int r = 0; r < 4; ++r) {
                const int m = m0 + wm + mt * 16 + qd * 4 + r;
                const float val = acc[mt][nt][r] + bv;
                if (EPI == 0) {
                    obf[(size_t)m * N_ + col] = f2bf(val);
                } else {
                    const int win = m / 49, l = m - win * 49;
                    const int b = win >> 6, wh = (win >> 3) & 7, ww = win & 7;
                    const int i = l / 7, j = l - i * 7;
                    const size_t sr = ((size_t)b * 3136 + (wh * 7 + i) * 56 + (ww * 7 + j)) * 384 + col;
                    oflt[sr] = xres[sr] + val;
                }
            }
        }
    }
}

// ---------------- attention: one wave per (window, head) ----------------
__global__ __launch_bounds__(256) void attn_kernel(
    const unsigned short* __restrict__ qkv, unsigned short* __restrict__ o)
{
    __shared__ unsigned short P[4][64 * 72];   // per-wave, stride 72 (16B-aligned rows, 2-way banks)
    const int lane = threadIdx.x & 63;
    const int wv   = threadIdx.x >> 6;
    const int cl = lane & 15;
    const int qd = lane >> 4;
    const int g   = blockIdx.x * 4 + wv;
    const int win = g / 12;
    const int h   = g - win * 12;
    const unsigned short* base = qkv + (size_t)win * (49 * 1152);

    // S = Q @ K^T  (64x64 padded, K=32)
    bf16x8 aq[4], bk[4];
#pragma unroll
    for (int mt = 0; mt < 4; ++mt) {
        const int l = mt * 16 + cl;
        bf16x8 z = {};
        if (l < 49) z = *(const bf16x8*)(base + (size_t)l * 1152 + h * 32 + qd * 8);
        aq[mt] = z;
    }
#pragma unroll
    for (int nt = 0; nt < 4; ++nt) {
        const int lk = nt * 16 + cl;
        bf16x8 z = {};
        if (lk < 49) z = *(const bf16x8*)(base + (size_t)lk * 1152 + 384 + h * 32 + qd * 8);
        bk[nt] = z;
    }
    f32x4 s[4][4] = {};
#pragma unroll
    for (int mt = 0; mt < 4; ++mt)
#pragma unroll
        for (int nt = 0; nt < 4; ++nt)
            s[mt][nt] = __builtin_amdgcn_mfma_f32_16x16x32_bf16(aq[mt], bk[nt], s[mt][nt], 0, 0, 0);

    const float scale = 0.17677669529663687f;   // 1/sqrt(32)
#pragma unroll
    for (int mt = 0; mt < 4; ++mt)
#pragma unroll
        for (int nt = 0; nt < 4; ++nt)
#pragma unroll
            for (int r = 0; r < 4; ++r) {
                float t = s[mt][nt][r] * scale;
                if (nt * 16 + cl >= 49) t = -1e30f;
                s[mt][nt][r] = t;
            }

    // softmax over rows (row lives across lane&15 and the 4 nt-accs)
#pragma unroll
    for (int mt = 0; mt < 4; ++mt)
#pragma unroll
        for (int r = 0; r < 4; ++r) {
            float mx = fmaxf(fmaxf(s[mt][0][r], s[mt][1][r]), fmaxf(s[mt][2][r], s[mt][3][r]));
            mx = fmaxf(mx, __shfl_xor(mx, 1, 64));
            mx = fmaxf(mx, __shfl_xor(mx, 2, 64));
            mx = fmaxf(mx, __shfl_xor(mx, 4, 64));
            mx = fmaxf(mx, __shfl_xor(mx, 8, 64));
            float sm = 0.f;
#pragma unroll
            for (int nt = 0; nt < 4; ++nt) {
                const float p = __expf(s[mt][nt][r] - mx);
                s[mt][nt][r] = p;
                sm += p;
            }
            sm += __shfl_xor(sm, 1, 64);
            sm += __shfl_xor(sm, 2, 64);
            sm += __shfl_xor(sm, 4, 64);
            sm += __shfl_xor(sm, 8, 64);
            const float inv = 1.f / sm;
#pragma unroll
            for (int nt = 0; nt < 4; ++nt)
                s[mt][nt][r] *= inv;
        }

    // P -> LDS (C-layout scatter), read back in A-layout
    unsigned short* Pw = &P[wv][0];
#pragma unroll
    for (int mt = 0; mt < 4; ++mt)
#pragma unroll
        for (int nt = 0; nt < 4; ++nt)
#pragma unroll
            for (int r = 0; r < 4; ++r)
                Pw[(mt * 16 + qd * 4 + r) * 72 + nt * 16 + cl] = f2bf(s[mt][nt][r]);

    // O = P @ V   (64x32, K=64)
    f32x4 oa[4][2] = {};
    const unsigned short* vbase = base + 768 + h * 32;
#pragma unroll
    for (int kk = 0; kk < 2; ++kk) {
        bf16x8 ap[4];
#pragma unroll
        for (int mt = 0; mt < 4; ++mt)
            ap[mt] = *(const bf16x8*)(Pw + (mt * 16 + cl) * 72 + kk * 32 + qd * 8);
#pragma unroll
        for (int nt = 0; nt < 2; ++nt) {
            ushort8 tv;
#pragma unroll
            for (int jj = 0; jj < 8; ++jj) {
                const int lk = kk * 32 + qd * 8 + jj;
                tv[jj] = (lk < 49) ? vbase[(size_t)lk * 1152 + nt * 16 + cl] : (unsigned short)0;
            }
            const bf16x8 bv = __builtin_bit_cast(bf16x8, tv);
#pragma unroll
            for (int mt = 0; mt < 4; ++mt)
                oa[mt][nt] = __builtin_amdgcn_mfma_f32_16x16x32_bf16(ap[mt], bv, oa[mt][nt], 0, 0, 0);
        }
    }

    unsigned short* ob = o + (size_t)win * 49 * 384 + h * 32;
#pragma unroll
    for (int mt = 0; mt < 4; ++mt)
#pragma unroll
        for (int r = 0; r < 4; ++r) {
            const int l = mt * 16 + qd * 4 + r;
            if (l < 49) {
#pragma unroll
                for (int nt = 0; nt < 2; ++nt)
                    ob[(size_t)l * 384 + nt * 16 + cl] = f2bf(oa[mt][nt][r]);
            }
        }
}

extern "C" void kernel_launch(void* const* d_in, const int* in_sizes, int n_in,
                              void* d_out, int out_size, void* d_ws, size_t ws_size,
                              hipStream_t stream)
{
    const float* x   = (const float*)d_in[0];
    const float* gam = (const float*)d_in[1];
    const float* bet = (const float*)d_in[2];
    const float* wi  = (const float*)d_in[3];
    const float* bi  = (const float*)d_in[4];
    const float* wo  = (const float*)d_in[5];
    const float* bo  = (const float*)d_in[6];
    float* out = (float*)d_out;

    const int Bb   = in_sizes[0] / (3136 * 384);  // 32
    const int M    = Bb * 3136;                   // 100352 (= NWIN*49)
    const int NWIN = Bb * 64;

    char* ws = (char*)d_ws;
    unsigned short* qw   = (unsigned short*)(ws);                                   // w_in bf16
    unsigned short* ow   = (unsigned short*)(ws + 884736);                          // w_out bf16
    unsigned short* y    = (unsigned short*)(ws + 1179648);                         // [M,384] bf16
    unsigned short* qkv  = (unsigned short*)(ws + 1179648 + (size_t)M * 768);       // [M,1152] bf16
    unsigned short* owin = (unsigned short*)(ws + 1179648 + (size_t)M * 768 + (size_t)M * 2304); // [M,384] bf16

    convw_kernel<<<1728, 256, 0, stream>>>(wi, wo, qw, ow);
    ln_kernel<<<M / 4, 256, 0, stream>>>(x, gam, bet, y);
    gemm_kernel<1152, 0><<<dim3(9, M / 128), 256, 0, stream>>>(y, qw, bi, qkv, nullptr, nullptr);
    attn_kernel<<<NWIN * 12 / 4, 256, 0, stream>>>(qkv, owin);
    gemm_kernel<384, 1><<<dim3(3, M / 128), 256, 0, stream>>>(owin, ow, bo, nullptr, x, out);
}